// Round 13
// baseline (222.220 us; speedup 1.0000x reference)
//
#include <hip/hip_runtime.h>
#include <hip/hip_bf16.h>

typedef _Float16 f16;
typedef f16 f16x8 __attribute__((ext_vector_type(8)));
typedef f16 f16x2 __attribute__((ext_vector_type(2)));
typedef float f32x4 __attribute__((ext_vector_type(4)));
typedef unsigned int u32;

#define MFMA16(a, b, c) __builtin_amdgcn_mfma_f32_16x16x32_f16((a), (b), (c), 0, 0, 0)

__device__ __forceinline__ u32 pkrz(float a, float b) {
    auto r = __builtin_amdgcn_cvt_pkrtz(a, b);
    return __builtin_bit_cast(u32, r);
}
__device__ __forceinline__ u32 pkmax0(u32 x) {
    f16x2 h = __builtin_bit_cast(f16x2, x);
    f16x2 z = {(f16)0.f, (f16)0.f};
    f16x2 m = __builtin_elementwise_max(h, z);
    return __builtin_bit_cast(u32, m);
}
__device__ __forceinline__ u32 pkrelu(float a, float b) {
    return pkmax0(pkrz(a, b));
}

union U8 { f16x8 h; u32 w[4]; };

// ---- ws layout (float offsets) ----
#define OFF_Y      4096       // 1,089,536 floats: [spt_pos 20480][spt_neg 20480][qry 1048576]

__device__ __forceinline__ int b_of(int e) {
    if (e < 20480) return e / 1280;
    if (e < 40960) return (e - 20480) / 1280;
    return (e - 40960) >> 16;
}

// ---------------- fused main: per-block prep + all-register MLP chain ----------------
// 1064 blocks x 4 waves x 4 iters x 64 elems = 1,089,536
// Hidden-channel permutation: B-position (kk,g,i) holds C-slot
// (2kk + (i>>2))*16 + g*4 + (i&3) of the previous layer -> layer transition is
// pure in-register relu+pack. L2 weights stream from LDS, one read per 2 chunks.
// launch_bounds(256,4): VGPR 108 <= 128 and LDS 33KB allow 4 blocks/CU; the
// serial L1->L2->L3->L4 chain is latency-bound and needs the residency.
__global__ __launch_bounds__(256, 4) void k_main(
    const float* __restrict__ sup, const float* __restrict__ supn,
    const float* __restrict__ qry, const float* __restrict__ neg,
    const float* __restrict__ w1, const float* __restrict__ b1p,
    const float* __restrict__ w2, const float* __restrict__ w3,
    const float* __restrict__ w4, const float* __restrict__ b2p,
    const float* __restrict__ b3p, const float* __restrict__ b4p,
    float* __restrict__ ws)
{
    __shared__ __align__(16) f16x8 w2lds[16 * 64];   // 16 KB: L2 frags
    __shared__ __align__(16) f16x8 wpk[13 * 64];     // 13 KB: L1(0..7), L3(8..11), L4(12)
    __shared__ uint2 stage[4][64];                   // 2 KB
    __shared__ float relb[2][256];                   // 2 KB
    float* wsY = ws + OFF_Y;

    int tid = threadIdx.x, wv = tid >> 6, lane = tid & 63;
    int g = lane >> 4, col = lane & 15;
    const f32x4 zero4 = {0.f, 0.f, 0.f, 0.f};

    int blkbase = blockIdx.x * 1024;
    int rb0 = b_of(blkbase), rb1 = b_of(blkbase + 1023);

    // ---- per-block rel for the <=2 batch rows this block touches ----
    #pragma unroll
    for (int k = 0; k < 2; k++) {
        int bb = k ? rb1 : rb0;
        float acc = 0.f;
        #pragma unroll
        for (int n = 0; n < 5; n++) {
            const float* base = sup + ((bb * 5 + n) * 2) * 256 + tid;
            acc += base[256] - base[0];
        }
        relb[k][tid] = acc * 0.2f;
    }

    // ---- per-block W2 fragment packing into LDS (frag f: t=f>>2, kk=f&3) ----
    #pragma unroll
    for (int i = 0; i < 4; i++) {
        int id = tid + 256 * i;                      // 0..1023
        int f = id >> 6, ln = id & 63;
        int gg = ln >> 4, cr = ln & 15;
        int t = f >> 2, kk = f & 3, out = t * 16 + cr;
        U8 v;
        #pragma unroll
        for (int i2 = 0; i2 < 8; i2++) {
            int u = (2 * kk + (i2 >> 2)) * 16 + gg * 4 + (i2 & 3);
            v.h[i2] = (f16)w2[out * 128 + u];
        }
        w2lds[id] = v.h;
    }
    // ---- per-block W1/W3/W4 fragment packing ----
    for (int id = tid; id < 13 * 64; id += 256) {
        int fi = id >> 6, ln = id & 63;
        int gg = ln >> 4, cr = ln & 15, kb = gg * 8;
        U8 v;
        if (fi < 8) {                                 // L1 + b1 folded at k==3
            int out = fi * 16 + cr;
            #pragma unroll
            for (int i2 = 0; i2 < 8; i2++) {
                int k = kb + i2;
                v.h[i2] = (f16)((k < 3) ? w1[out * 3 + k] : (k == 3 ? b1p[out] : 0.f));
            }
        } else if (fi < 12) {                         // L3, permuted input cols
            int f = fi - 8; int t = f >> 1, kk = f & 1; int out = t * 16 + cr;
            #pragma unroll
            for (int i2 = 0; i2 < 8; i2++) {
                int u = (2 * kk + (i2 >> 2)) * 16 + gg * 4 + (i2 & 3);
                v.h[i2] = (f16)w3[out * 64 + u];
            }
        } else {                                      // L4, rows 1..15 zero
            #pragma unroll
            for (int i2 = 0; i2 < 8; i2++) {
                int u = (i2 >> 2) * 16 + gg * 4 + (i2 & 3);
                v.h[i2] = (f16)((cr == 0) ? w4[u] : 0.f);
            }
        }
        wpk[id] = v.h;
    }
    __syncthreads();

    // register frags for small layers
    f16x8 w1f[8], w3f[4], w4f;
    #pragma unroll
    for (int f = 0; f < 8; f++) w1f[f] = wpk[f * 64 + lane];
    #pragma unroll
    for (int f = 0; f < 4; f++) w3f[f] = wpk[(8 + f) * 64 + lane];
    w4f = wpk[12 * 64 + lane];

    f32x4 bias2[4], bias3[2];
    #pragma unroll
    for (int t = 0; t < 4; t++) {
        int o = t * 16 + g * 4;
        bias2[t] = (f32x4){b2p[o], b2p[o + 1], b2p[o + 2], b2p[o + 3]};
    }
    #pragma unroll
    for (int t = 0; t < 2; t++) {
        int o = t * 16 + g * 4;
        bias3[t] = (f32x4){b3p[o], b3p[o + 1], b3p[o + 2], b3p[o + 3]};
    }
    float b4v = b4p[0];

    int base = blkbase + wv * 256;

    for (int it = 0; it < 4; ++it) {
        // ---- all-lane coalesced input load: one element per lane ----
        int e = base + it * 64 + lane;
        const float* hp; int bb, dd;
        if (e < 40960) {
            int e2 = (e < 20480) ? e : e - 20480;
            bb = e2 / 1280; int r = e2 - bb * 1280;
            int n = r >> 8; dd = r & 255;
            const float* srcp = (e < 20480) ? sup : supn;
            hp = srcp + ((bb * 5 + n) * 2) * 256 + dd;
        } else {
            int e2 = e - 40960;
            bb = e2 >> 16; int r = e2 & 65535, m = r >> 8; dd = r & 255;
            hp = (m < 128) ? (qry + ((bb * 128 + m) * 2) * 256 + dd)
                           : (neg + ((bb * 128 + (m - 128)) * 2) * 256 + dd);
        }
        float x0 = hp[0], x2 = hp[256];
        float x1 = relb[(bb == rb0) ? 0 : 1][dd];
        stage[wv][lane] = make_uint2(pkrz(x0, x1), pkrz(x2, 1.0f));

        #pragma unroll
        for (int jp = 0; jp < 2; ++jp) {             // 2 chunk-pairs
            // B1 for chunks a=(2jp), b=(2jp+1)
            U8 b1a, b1b;
            #pragma unroll
            for (int q = 0; q < 4; q++) { b1a.w[q] = 0u; b1b.w[q] = 0u; }
            if (g == 0) {
                uint2 sa = stage[wv][(2 * jp) * 16 + col];
                uint2 sb = stage[wv][(2 * jp + 1) * 16 + col];
                b1a.w[0] = sa.x; b1a.w[1] = sa.y;
                b1b.w[0] = sb.x; b1b.w[1] = sb.y;
            }

            // L1: 8 tiles x 2 chunks
            f32x4 c1a[8], c1b[8];
            #pragma unroll
            for (int t = 0; t < 8; t++) {
                c1a[t] = MFMA16(w1f[t], b1a.h, zero4);
                c1b[t] = MFMA16(w1f[t], b1b.h, zero4);
            }

            U8 b2fa[4], b2fb[4];
            #pragma unroll
            for (int kk = 0; kk < 4; kk++) {
                b2fa[kk].w[0] = pkrelu(c1a[2 * kk][0],     c1a[2 * kk][1]);
                b2fa[kk].w[1] = pkrelu(c1a[2 * kk][2],     c1a[2 * kk][3]);
                b2fa[kk].w[2] = pkrelu(c1a[2 * kk + 1][0], c1a[2 * kk + 1][1]);
                b2fa[kk].w[3] = pkrelu(c1a[2 * kk + 1][2], c1a[2 * kk + 1][3]);
                b2fb[kk].w[0] = pkrelu(c1b[2 * kk][0],     c1b[2 * kk][1]);
                b2fb[kk].w[1] = pkrelu(c1b[2 * kk][2],     c1b[2 * kk][3]);
                b2fb[kk].w[2] = pkrelu(c1b[2 * kk + 1][0], c1b[2 * kk + 1][1]);
                b2fb[kk].w[3] = pkrelu(c1b[2 * kk + 1][2], c1b[2 * kk + 1][3]);
            }

            // L2: one LDS weight read feeds both chunks
            f32x4 c2a[4], c2b[4];
            #pragma unroll
            for (int t = 0; t < 4; t++) {
                f32x4 ca = bias2[t], cb = bias2[t];
                #pragma unroll
                for (int kk = 0; kk < 4; kk++) {
                    f16x8 wfr = w2lds[(t * 4 + kk) * 64 + lane];
                    ca = MFMA16(wfr, b2fa[kk].h, ca);
                    cb = MFMA16(wfr, b2fb[kk].h, cb);
                }
                c2a[t] = ca; c2b[t] = cb;
            }

            U8 b3fa[2], b3fb[2];
            #pragma unroll
            for (int kk = 0; kk < 2; kk++) {
                b3fa[kk].w[0] = pkrelu(c2a[2 * kk][0],     c2a[2 * kk][1]);
                b3fa[kk].w[1] = pkrelu(c2a[2 * kk][2],     c2a[2 * kk][3]);
                b3fa[kk].w[2] = pkrelu(c2a[2 * kk + 1][0], c2a[2 * kk + 1][1]);
                b3fa[kk].w[3] = pkrelu(c2a[2 * kk + 1][2], c2a[2 * kk + 1][3]);
                b3fb[kk].w[0] = pkrelu(c2b[2 * kk][0],     c2b[2 * kk][1]);
                b3fb[kk].w[1] = pkrelu(c2b[2 * kk][2],     c2b[2 * kk][3]);
                b3fb[kk].w[2] = pkrelu(c2b[2 * kk + 1][0], c2b[2 * kk + 1][1]);
                b3fb[kk].w[3] = pkrelu(c2b[2 * kk + 1][2], c2b[2 * kk + 1][3]);
            }

            // L3
            f32x4 c3a[2], c3b[2];
            #pragma unroll
            for (int t = 0; t < 2; t++) {
                f32x4 ca = bias3[t], cb = bias3[t];
                #pragma unroll
                for (int kk = 0; kk < 2; kk++) {
                    ca = MFMA16(w3f[t * 2 + kk], b3fa[kk].h, ca);
                    cb = MFMA16(w3f[t * 2 + kk], b3fb[kk].h, cb);
                }
                c3a[t] = ca; c3b[t] = cb;
            }

            U8 b4fa, b4fb;
            b4fa.w[0] = pkrelu(c3a[0][0], c3a[0][1]);
            b4fa.w[1] = pkrelu(c3a[0][2], c3a[0][3]);
            b4fa.w[2] = pkrelu(c3a[1][0], c3a[1][1]);
            b4fa.w[3] = pkrelu(c3a[1][2], c3a[1][3]);
            b4fb.w[0] = pkrelu(c3b[0][0], c3b[0][1]);
            b4fb.w[1] = pkrelu(c3b[0][2], c3b[0][3]);
            b4fb.w[2] = pkrelu(c3b[1][0], c3b[1][1]);
            b4fb.w[3] = pkrelu(c3b[1][2], c3b[1][3]);

            // L4
            f32x4 c4a = MFMA16(w4f, b4fa.h, zero4);
            f32x4 c4b = MFMA16(w4f, b4fb.h, zero4);
            if (lane < 16) {
                wsY[base + it * 64 + (2 * jp) * 16 + lane]     = c4a[0] + b4v;
                wsY[base + it * 64 + (2 * jp + 1) * 16 + lane] = c4b[0] + b4v;
            }
        }
    }
}

// ---------------- scores (+ in-block proto/sneg means): one wave per row ----------------
__global__ __launch_bounds__(256) void k_scores(float* __restrict__ ws, float* __restrict__ out)
{
    __shared__ float proto[16][256];   // 16 KB
    __shared__ float snegs[256];       // 1 KB
    const float* y = ws + OFF_Y;
    int tid = threadIdx.x;
    int row0 = blockIdx.x * 4;
    int b = row0 >> 8;                 // 4 rows per block share b

    // proto[c][d] = mean_n Y[spt_pos: c*1280+n*256+d]
    #pragma unroll
    for (int i = 0; i < 16; i++) {
        int idx = tid + 256 * i;       // 0..4095
        int c = idx >> 8, d = idx & 255;
        float s = 0.f;
        #pragma unroll
        for (int n = 0; n < 5; n++) s += y[c * 1280 + n * 256 + d];
        proto[c][d] = s * 0.2f;
    }
    {
        float s = 0.f;
        #pragma unroll
        for (int n = 0; n < 5; n++) s += y[20480 + b * 1280 + n * 256 + tid];
        snegs[tid] = s * 0.2f;
    }
    __syncthreads();

    int row = row0 + (tid >> 6);
    int lane = tid & 63;
    int m = row & 255;
    const float* q = y + 40960 + row * 256;
    float q0 = q[lane], q1 = q[lane + 64], q2 = q[lane + 128], q3 = q[lane + 192];

    float s[17];
    #pragma unroll
    for (int c = 0; c < 16; c++) {
        float d0 = q0 - proto[c][lane],       d1 = q1 - proto[c][lane + 64];
        float d2 = q2 - proto[c][lane + 128], d3 = q3 - proto[c][lane + 192];
        s[c] = d0 * d0 + d1 * d1 + d2 * d2 + d3 * d3;
    }
    {
        float d0 = q0 - snegs[lane],       d1 = q1 - snegs[lane + 64];
        float d2 = q2 - snegs[lane + 128], d3 = q3 - snegs[lane + 192];
        s[16] = d0 * d0 + d1 * d1 + d2 * d2 + d3 * d3;
    }
    #pragma unroll
    for (int off = 32; off > 0; off >>= 1) {
        #pragma unroll
        for (int c = 0; c < 17; c++) s[c] += __shfl_xor(s[c], off, 64);
    }
    float sumd = 0.f, selfd = 0.f;
    #pragma unroll
    for (int c = 0; c < 16; c++) {
        float dc = sqrtf(s[c]);
        sumd += dc;
        if (c == b) selfd = dc;
    }
    float qpos = -selfd;
    float qneg = -sqrtf(s[16]);
    float relation = -(sumd - selfd) * (1.f / 15.f);
    float delta = qpos - qneg - 0.3f * relation;

    if (lane == 0) {
        out[2 * row] = qpos;
        out[2 * row + 1] = qneg;
        out[8192 + row] = (m < 128) ? 0.f : 1.f;
        if (m < 128) out[12288 + b * 128 + m] = delta;
        else         out[14336 + b * 128 + (m - 128)] = delta;
    }
}

// ---------------- delta_loss finisher: reduce over out[] ----------------
__global__ __launch_bounds__(256) void k_final(float* __restrict__ out)
{
    __shared__ float red[2][256];
    int t = threadIdx.x;
    float sp = 0.f, sn = 0.f;
    #pragma unroll
    for (int i = 0; i < 8; i++) {
        int idx = t + 256 * i;            // 2048 (b, m<128) rows
        int b = idx >> 7, m = idx & 127;
        int row = b * 256 + m;
        sp += out[2 * row];
        sn += out[2 * row + 1];
    }
    red[0][t] = sp; red[1][t] = sn;
    __syncthreads();
    #pragma unroll
    for (int off = 128; off > 0; off >>= 1) {
        if (t < off) { red[0][t] += red[0][t + off]; red[1][t] += red[1][t + off]; }
        __syncthreads();
    }
    if (t == 0) {
        float v = (red[0][0] - red[1][0]) * (1.f / 2048.f) + 1.f;
        out[16384] = fmaxf(v, 0.f);
    }
}

extern "C" void kernel_launch(void* const* d_in, const int* in_sizes, int n_in,
                              void* d_out, int out_size, void* d_ws, size_t ws_size,
                              hipStream_t stream)
{
    const float* sup  = (const float*)d_in[0];
    const float* supn = (const float*)d_in[1];
    const float* qry  = (const float*)d_in[2];
    const float* neg  = (const float*)d_in[3];
    const float* w1   = (const float*)d_in[4];
    const float* b1   = (const float*)d_in[5];
    const float* w2   = (const float*)d_in[6];
    const float* b2   = (const float*)d_in[7];
    const float* w3   = (const float*)d_in[8];
    const float* b3   = (const float*)d_in[9];
    const float* w4   = (const float*)d_in[10];
    const float* b4   = (const float*)d_in[11];
    float* ws  = (float*)d_ws;
    float* out = (float*)d_out;

    k_main  <<<1064, 256, 0, stream>>>(sup, supn, qry, neg, w1, b1, w2, w3, w4, b2, b3, b4, ws);
    k_scores<<<1024, 256, 0, stream>>>(ws, out);
    k_final <<<1,    256, 0, stream>>>(out);
}

// Round 15
// 133.394 us; speedup vs baseline: 1.6659x; 1.6659x over previous
//
#include <hip/hip_runtime.h>
#include <hip/hip_bf16.h>

typedef _Float16 f16;
typedef f16 f16x8 __attribute__((ext_vector_type(8)));
typedef f16 f16x2 __attribute__((ext_vector_type(2)));
typedef float f32x4 __attribute__((ext_vector_type(4)));
typedef unsigned int u32;

#define MFMA16(a, b, c) __builtin_amdgcn_mfma_f32_16x16x32_f16((a), (b), (c), 0, 0, 0)

__device__ __forceinline__ u32 pkrz(float a, float b) {
    auto r = __builtin_amdgcn_cvt_pkrtz(a, b);
    return __builtin_bit_cast(u32, r);
}
__device__ __forceinline__ u32 pkmax0(u32 x) {
    f16x2 h = __builtin_bit_cast(f16x2, x);
    f16x2 z = {(f16)0.f, (f16)0.f};
    f16x2 m = __builtin_elementwise_max(h, z);
    return __builtin_bit_cast(u32, m);
}
__device__ __forceinline__ u32 pkrelu(float a, float b) {
    return pkmax0(pkrz(a, b));
}

union U8 { f16x8 h; u32 w[4]; };

// ---- ws layout (float offsets) ----
#define OFF_Y      4096       // 1,089,536 floats: [spt_pos 20480][spt_neg 20480][qry 1048576]
#define OFF_PROTO  1093632    // 4096
#define OFF_SNEG   1097728    // 4096

__device__ __forceinline__ int b_of(int e) {
    if (e < 20480) return e / 1280;
    if (e < 40960) return (e - 20480) / 1280;
    return (e - 40960) >> 16;
}

// ---------------- fused main: per-block prep + all-register MLP chain ----------------
// 1064 blocks x 4 waves x 4 iters x 64 elems = 1,089,536
// Hidden-channel permutation: B-position (kk,g,i) holds C-slot
// (2kk + (i>>2))*16 + g*4 + (i&3) of the previous layer -> layer transition is
// pure in-register relu+pack. L2 weights stream from LDS, one read per 2 chunks.
// launch_bounds(256,2): DO NOT raise to 4 — it caps VGPR at 64 and forces
// massive scratch spills (R13: FETCH 5MB->291MB, k_main 42->134us).
__global__ __launch_bounds__(256, 2) void k_main(
    const float* __restrict__ sup, const float* __restrict__ supn,
    const float* __restrict__ qry, const float* __restrict__ neg,
    const float* __restrict__ w1, const float* __restrict__ b1p,
    const float* __restrict__ w2, const float* __restrict__ w3,
    const float* __restrict__ w4, const float* __restrict__ b2p,
    const float* __restrict__ b3p, const float* __restrict__ b4p,
    float* __restrict__ ws)
{
    __shared__ __align__(16) f16x8 w2lds[16 * 64];   // 16 KB: L2 frags
    __shared__ __align__(16) f16x8 wpk[13 * 64];     // 13 KB: L1(0..7), L3(8..11), L4(12)
    __shared__ uint2 stage[4][64];                   // 2 KB
    __shared__ float relb[2][256];                   // 2 KB
    float* wsY = ws + OFF_Y;

    int tid = threadIdx.x, wv = tid >> 6, lane = tid & 63;
    int g = lane >> 4, col = lane & 15;
    const f32x4 zero4 = {0.f, 0.f, 0.f, 0.f};

    int blkbase = blockIdx.x * 1024;
    int rb0 = b_of(blkbase), rb1 = b_of(blkbase + 1023);

    // ---- per-block rel for the <=2 batch rows this block touches ----
    #pragma unroll
    for (int k = 0; k < 2; k++) {
        int bb = k ? rb1 : rb0;
        float acc = 0.f;
        #pragma unroll
        for (int n = 0; n < 5; n++) {
            const float* base = sup + ((bb * 5 + n) * 2) * 256 + tid;
            acc += base[256] - base[0];
        }
        relb[k][tid] = acc * 0.2f;
    }

    // ---- per-block W2 fragment packing into LDS (frag f: t=f>>2, kk=f&3) ----
    #pragma unroll
    for (int i = 0; i < 4; i++) {
        int id = tid + 256 * i;                      // 0..1023
        int f = id >> 6, ln = id & 63;
        int gg = ln >> 4, cr = ln & 15;
        int t = f >> 2, kk = f & 3, out = t * 16 + cr;
        U8 v;
        #pragma unroll
        for (int i2 = 0; i2 < 8; i2++) {
            int u = (2 * kk + (i2 >> 2)) * 16 + gg * 4 + (i2 & 3);
            v.h[i2] = (f16)w2[out * 128 + u];
        }
        w2lds[id] = v.h;
    }
    // ---- per-block W1/W3/W4 fragment packing ----
    for (int id = tid; id < 13 * 64; id += 256) {
        int fi = id >> 6, ln = id & 63;
        int gg = ln >> 4, cr = ln & 15, kb = gg * 8;
        U8 v;
        if (fi < 8) {                                 // L1 + b1 folded at k==3
            int out = fi * 16 + cr;
            #pragma unroll
            for (int i2 = 0; i2 < 8; i2++) {
                int k = kb + i2;
                v.h[i2] = (f16)((k < 3) ? w1[out * 3 + k] : (k == 3 ? b1p[out] : 0.f));
            }
        } else if (fi < 12) {                         // L3, permuted input cols
            int f = fi - 8; int t = f >> 1, kk = f & 1; int out = t * 16 + cr;
            #pragma unroll
            for (int i2 = 0; i2 < 8; i2++) {
                int u = (2 * kk + (i2 >> 2)) * 16 + gg * 4 + (i2 & 3);
                v.h[i2] = (f16)w3[out * 64 + u];
            }
        } else {                                      // L4, rows 1..15 zero
            #pragma unroll
            for (int i2 = 0; i2 < 8; i2++) {
                int u = (i2 >> 2) * 16 + gg * 4 + (i2 & 3);
                v.h[i2] = (f16)((cr == 0) ? w4[u] : 0.f);
            }
        }
        wpk[id] = v.h;
    }
    __syncthreads();

    // register frags for small layers
    f16x8 w1f[8], w3f[4], w4f;
    #pragma unroll
    for (int f = 0; f < 8; f++) w1f[f] = wpk[f * 64 + lane];
    #pragma unroll
    for (int f = 0; f < 4; f++) w3f[f] = wpk[(8 + f) * 64 + lane];
    w4f = wpk[12 * 64 + lane];

    f32x4 bias2[4], bias3[2];
    #pragma unroll
    for (int t = 0; t < 4; t++) {
        int o = t * 16 + g * 4;
        bias2[t] = (f32x4){b2p[o], b2p[o + 1], b2p[o + 2], b2p[o + 3]};
    }
    #pragma unroll
    for (int t = 0; t < 2; t++) {
        int o = t * 16 + g * 4;
        bias3[t] = (f32x4){b3p[o], b3p[o + 1], b3p[o + 2], b3p[o + 3]};
    }
    float b4v = b4p[0];

    int base = blkbase + wv * 256;

    for (int it = 0; it < 4; ++it) {
        // ---- all-lane coalesced input load: one element per lane ----
        int e = base + it * 64 + lane;
        const float* hp; int bb, dd;
        if (e < 40960) {
            int e2 = (e < 20480) ? e : e - 20480;
            bb = e2 / 1280; int r = e2 - bb * 1280;
            int n = r >> 8; dd = r & 255;
            const float* srcp = (e < 20480) ? sup : supn;
            hp = srcp + ((bb * 5 + n) * 2) * 256 + dd;
        } else {
            int e2 = e - 40960;
            bb = e2 >> 16; int r = e2 & 65535, m = r >> 8; dd = r & 255;
            hp = (m < 128) ? (qry + ((bb * 128 + m) * 2) * 256 + dd)
                           : (neg + ((bb * 128 + (m - 128)) * 2) * 256 + dd);
        }
        float x0 = hp[0], x2 = hp[256];
        float x1 = relb[(bb == rb0) ? 0 : 1][dd];
        stage[wv][lane] = make_uint2(pkrz(x0, x1), pkrz(x2, 1.0f));

        #pragma unroll
        for (int jp = 0; jp < 2; ++jp) {             // 2 chunk-pairs
            // B1 for chunks a=(2jp), b=(2jp+1)
            U8 b1a, b1b;
            #pragma unroll
            for (int q = 0; q < 4; q++) { b1a.w[q] = 0u; b1b.w[q] = 0u; }
            if (g == 0) {
                uint2 sa = stage[wv][(2 * jp) * 16 + col];
                uint2 sb = stage[wv][(2 * jp + 1) * 16 + col];
                b1a.w[0] = sa.x; b1a.w[1] = sa.y;
                b1b.w[0] = sb.x; b1b.w[1] = sb.y;
            }

            // L1: 8 tiles x 2 chunks
            f32x4 c1a[8], c1b[8];
            #pragma unroll
            for (int t = 0; t < 8; t++) {
                c1a[t] = MFMA16(w1f[t], b1a.h, zero4);
                c1b[t] = MFMA16(w1f[t], b1b.h, zero4);
            }

            U8 b2fa[4], b2fb[4];
            #pragma unroll
            for (int kk = 0; kk < 4; kk++) {
                b2fa[kk].w[0] = pkrelu(c1a[2 * kk][0],     c1a[2 * kk][1]);
                b2fa[kk].w[1] = pkrelu(c1a[2 * kk][2],     c1a[2 * kk][3]);
                b2fa[kk].w[2] = pkrelu(c1a[2 * kk + 1][0], c1a[2 * kk + 1][1]);
                b2fa[kk].w[3] = pkrelu(c1a[2 * kk + 1][2], c1a[2 * kk + 1][3]);
                b2fb[kk].w[0] = pkrelu(c1b[2 * kk][0],     c1b[2 * kk][1]);
                b2fb[kk].w[1] = pkrelu(c1b[2 * kk][2],     c1b[2 * kk][3]);
                b2fb[kk].w[2] = pkrelu(c1b[2 * kk + 1][0], c1b[2 * kk + 1][1]);
                b2fb[kk].w[3] = pkrelu(c1b[2 * kk + 1][2], c1b[2 * kk + 1][3]);
            }

            // L2: one LDS weight read feeds both chunks
            f32x4 c2a[4], c2b[4];
            #pragma unroll
            for (int t = 0; t < 4; t++) {
                f32x4 ca = bias2[t], cb = bias2[t];
                #pragma unroll
                for (int kk = 0; kk < 4; kk++) {
                    f16x8 wfr = w2lds[(t * 4 + kk) * 64 + lane];
                    ca = MFMA16(wfr, b2fa[kk].h, ca);
                    cb = MFMA16(wfr, b2fb[kk].h, cb);
                }
                c2a[t] = ca; c2b[t] = cb;
            }

            U8 b3fa[2], b3fb[2];
            #pragma unroll
            for (int kk = 0; kk < 2; kk++) {
                b3fa[kk].w[0] = pkrelu(c2a[2 * kk][0],     c2a[2 * kk][1]);
                b3fa[kk].w[1] = pkrelu(c2a[2 * kk][2],     c2a[2 * kk][3]);
                b3fa[kk].w[2] = pkrelu(c2a[2 * kk + 1][0], c2a[2 * kk + 1][1]);
                b3fa[kk].w[3] = pkrelu(c2a[2 * kk + 1][2], c2a[2 * kk + 1][3]);
                b3fb[kk].w[0] = pkrelu(c2b[2 * kk][0],     c2b[2 * kk][1]);
                b3fb[kk].w[1] = pkrelu(c2b[2 * kk][2],     c2b[2 * kk][3]);
                b3fb[kk].w[2] = pkrelu(c2b[2 * kk + 1][0], c2b[2 * kk + 1][1]);
                b3fb[kk].w[3] = pkrelu(c2b[2 * kk + 1][2], c2b[2 * kk + 1][3]);
            }

            // L3
            f32x4 c3a[2], c3b[2];
            #pragma unroll
            for (int t = 0; t < 2; t++) {
                f32x4 ca = bias3[t], cb = bias3[t];
                #pragma unroll
                for (int kk = 0; kk < 2; kk++) {
                    ca = MFMA16(w3f[t * 2 + kk], b3fa[kk].h, ca);
                    cb = MFMA16(w3f[t * 2 + kk], b3fb[kk].h, cb);
                }
                c3a[t] = ca; c3b[t] = cb;
            }

            U8 b4fa, b4fb;
            b4fa.w[0] = pkrelu(c3a[0][0], c3a[0][1]);
            b4fa.w[1] = pkrelu(c3a[0][2], c3a[0][3]);
            b4fa.w[2] = pkrelu(c3a[1][0], c3a[1][1]);
            b4fa.w[3] = pkrelu(c3a[1][2], c3a[1][3]);
            b4fb.w[0] = pkrelu(c3b[0][0], c3b[0][1]);
            b4fb.w[1] = pkrelu(c3b[0][2], c3b[0][3]);
            b4fb.w[2] = pkrelu(c3b[1][0], c3b[1][1]);
            b4fb.w[3] = pkrelu(c3b[1][2], c3b[1][3]);

            // L4
            f32x4 c4a = MFMA16(w4f, b4fa.h, zero4);
            f32x4 c4b = MFMA16(w4f, b4fb.h, zero4);
            if (lane < 16) {
                wsY[base + it * 64 + (2 * jp) * 16 + lane]     = c4a[0] + b4v;
                wsY[base + it * 64 + (2 * jp + 1) * 16 + lane] = c4b[0] + b4v;
            }
        }
    }
}

// ---------------- proto / sneg means (once) ----------------
__global__ void k_means(float* __restrict__ ws)
{
    int idx = blockIdx.x * 256 + threadIdx.x;   // 4096 = (b,d)
    int b = idx >> 8, d = idx & 255;
    const float* y = ws + OFF_Y;
    float sp = 0.f, sn = 0.f;
    #pragma unroll
    for (int n = 0; n < 5; n++) {
        sp += y[b * 1280 + n * 256 + d];
        sn += y[20480 + b * 1280 + n * 256 + d];
    }
    ws[OFF_PROTO + idx] = sp * 0.2f;
    ws[OFF_SNEG + idx] = sn * 0.2f;
}

// ---------------- scores: 16 rows/block, proto staged in LDS once ----------------
// 256 blocks x 4 waves x 4 rows = 4096 rows; all 16 rows of a block share b.
__global__ __launch_bounds__(256) void k_scores(float* __restrict__ ws, float* __restrict__ out)
{
    __shared__ float proto[16][256];   // 16 KB
    __shared__ float snegs[256];       // 1 KB
    const float* y = ws + OFF_Y;
    int tid = threadIdx.x;
    int row0 = blockIdx.x * 16;
    int b = row0 >> 8;

    #pragma unroll
    for (int i = 0; i < 16; i++)
        proto[i][tid] = ws[OFF_PROTO + i * 256 + tid];
    snegs[tid] = ws[OFF_SNEG + b * 256 + tid];
    __syncthreads();

    int wv = tid >> 6, lane = tid & 63;

    for (int r = 0; r < 4; r++) {
        int row = row0 + wv * 4 + r;
        int m = row & 255;
        const float* q = y + 40960 + row * 256;
        float q0 = q[lane], q1 = q[lane + 64], q2 = q[lane + 128], q3 = q[lane + 192];

        float s[17];
        #pragma unroll
        for (int c = 0; c < 16; c++) {
            float d0 = q0 - proto[c][lane],       d1 = q1 - proto[c][lane + 64];
            float d2 = q2 - proto[c][lane + 128], d3 = q3 - proto[c][lane + 192];
            s[c] = d0 * d0 + d1 * d1 + d2 * d2 + d3 * d3;
        }
        {
            float d0 = q0 - snegs[lane],       d1 = q1 - snegs[lane + 64];
            float d2 = q2 - snegs[lane + 128], d3 = q3 - snegs[lane + 192];
            s[16] = d0 * d0 + d1 * d1 + d2 * d2 + d3 * d3;
        }
        #pragma unroll
        for (int off = 32; off > 0; off >>= 1) {
            #pragma unroll
            for (int c = 0; c < 17; c++) s[c] += __shfl_xor(s[c], off, 64);
        }
        float sumd = 0.f, selfd = 0.f;
        #pragma unroll
        for (int c = 0; c < 16; c++) {
            float dc = sqrtf(s[c]);
            sumd += dc;
            if (c == b) selfd = dc;
        }
        float qpos = -selfd;
        float qneg = -sqrtf(s[16]);
        float relation = -(sumd - selfd) * (1.f / 15.f);
        float delta = qpos - qneg - 0.3f * relation;

        if (lane == 0) {
            out[2 * row] = qpos;
            out[2 * row + 1] = qneg;
            out[8192 + row] = (m < 128) ? 0.f : 1.f;
            if (m < 128) out[12288 + b * 128 + m] = delta;
            else         out[14336 + b * 128 + (m - 128)] = delta;
        }
    }
}

// ---------------- delta_loss finisher: reduce over out[] ----------------
__global__ __launch_bounds__(256) void k_final(float* __restrict__ out)
{
    __shared__ float red[2][256];
    int t = threadIdx.x;
    float sp = 0.f, sn = 0.f;
    #pragma unroll
    for (int i = 0; i < 8; i++) {
        int idx = t + 256 * i;            // 2048 (b, m<128) rows
        int b = idx >> 7, m = idx & 127;
        int row = b * 256 + m;
        sp += out[2 * row];
        sn += out[2 * row + 1];
    }
    red[0][t] = sp; red[1][t] = sn;
    __syncthreads();
    #pragma unroll
    for (int off = 128; off > 0; off >>= 1) {
        if (t < off) { red[0][t] += red[0][t + off]; red[1][t] += red[1][t + off]; }
        __syncthreads();
    }
    if (t == 0) {
        float v = (red[0][0] - red[1][0]) * (1.f / 2048.f) + 1.f;
        out[16384] = fmaxf(v, 0.f);
    }
}

extern "C" void kernel_launch(void* const* d_in, const int* in_sizes, int n_in,
                              void* d_out, int out_size, void* d_ws, size_t ws_size,
                              hipStream_t stream)
{
    const float* sup  = (const float*)d_in[0];
    const float* supn = (const float*)d_in[1];
    const float* qry  = (const float*)d_in[2];
    const float* neg  = (const float*)d_in[3];
    const float* w1   = (const float*)d_in[4];
    const float* b1   = (const float*)d_in[5];
    const float* w2   = (const float*)d_in[6];
    const float* b2   = (const float*)d_in[7];
    const float* w3   = (const float*)d_in[8];
    const float* b3   = (const float*)d_in[9];
    const float* w4   = (const float*)d_in[10];
    const float* b4   = (const float*)d_in[11];
    float* ws  = (float*)d_ws;
    float* out = (float*)d_out;

    k_main  <<<1064, 256, 0, stream>>>(sup, supn, qry, neg, w1, b1, w2, w3, w4, b2, b3, b4, ws);
    k_means <<<16,   256, 0, stream>>>(ws);
    k_scores<<<256,  256, 0, stream>>>(ws, out);
    k_final <<<1,    256, 0, stream>>>(out);
}